// Round 3
// baseline (2098.212 us; speedup 1.0000x reference)
//
#include <hip/hip_runtime.h>

// Slater-determinant ordered sampler, D=512 sites, N=128 particles.
//
// Blocked N x N inverse-block recursion (same algebra as round 2, which
// passed): per block of B=32 sites, S = Pb A Pb^T drives a register-resident
// single-wave scan (identical decision logic to the reference); then
// A += (V U) D^-1 (V U)^T with V = A Pb^T.
//
// Round-3 execution fixes (round 2 regressed on spills/barriers/conflicts):
//  - amdgpu_waves_per_eu(2,2): VGPR cap 256 (8 waves = 2/SIMD exactly);
//    round 2 capped at 128 and spilled ~270 KB/dispatch to scratch.
//  - V reduced across waves via native LDS fp32 atomics into transposed
//    VT[32][132] -> 1 barrier instead of a 12-barrier slab tree.
//  - All lane-indexed LDS strides conflict-free (132 / 33); pad-36 arrays
//    only read at wave-uniform (broadcast) addresses.
//  - 6 barriers/block (96 total) vs 272.
// LDS: 18.4 (PbT/Wmat union) + 16.9 (VT) + 16.9 (WdT) + 4.2 (Smat)
//      + 4.6 (Umat) + misc = 61.2 KB < 64 KB.

#define DD 512
#define NN 128
#define BB 32
#define NTH 512
#define TINYF 1e-30f

__global__ __attribute__((amdgpu_flat_work_group_size(NTH, NTH),
                          amdgpu_waves_per_eu(2, 2)))
void slater_blk3(const float* __restrict__ P, const float* __restrict__ u,
                 float* __restrict__ out) {
  const int tid  = threadIdx.x;
  const int wave = tid >> 6;
  const int lane = tid & 63;
  const int c0   = wave << 4;

  __shared__ union PWU {
    float PbT[128][36];   // PbT[c][t] = P[i0+t][c]; rows read wave-uniform
    float Wmat[128][36];  // W row-major (overlay; PbT dead after S-phase)
  } PW;
  __shared__ float VT[32][132];   // VT[t][r] = V[r][t]
  __shared__ float WdT[32][132];  // WdT[t][r] = W[r][t] * invp[t]
  __shared__ float Smat[32][33];
  __shared__ float Umat[32][36];
  __shared__ float invpSh[32];
  __shared__ int   kSh;

  const float u_lo = u[lane];
  const float u_hi = u[lane + 64];

  // Zero cond_probs (harness poisons d_out). positions all get written.
  {
    const float4 z = make_float4(0.f, 0.f, 0.f, 0.f);
    float4* o4 = (float4*)out;
#pragma unroll
    for (int j = 0; j < 32; ++j) o4[tid + j * NTH] = z;
  }

  // A = I_N: wave w owns cols [16w,16w+16); lane l owns rows {l, l+64}.
  float A0[16], A1[16];
#pragma unroll
  for (int j = 0; j < 16; ++j) {
    A0[j] = (lane == c0 + j) ? 1.0f : 0.0f;
    A1[j] = (lane + 64 == c0 + j) ? 1.0f : 0.0f;
  }

  // Scan state (only wave 0's copy is live across blocks).
  float ratio = 1.0f, cumul = 0.0f;
  int k = 0;

  for (int blk = 0; blk < DD / BB; ++blk) {
    const int i0 = blk * BB;

    // ---- stage PbT + zero VT ----
    {
      const int t = tid & 31, cb = (tid >> 5) << 3;
      const float* src = P + (i0 + t) * NN + cb;
      const float4 a = *(const float4*)src;
      const float4 b = *(const float4*)(src + 4);
      PW.PbT[cb + 0][t] = a.x; PW.PbT[cb + 1][t] = a.y;
      PW.PbT[cb + 2][t] = a.z; PW.PbT[cb + 3][t] = a.w;
      PW.PbT[cb + 4][t] = b.x; PW.PbT[cb + 5][t] = b.y;
      PW.PbT[cb + 6][t] = b.z; PW.PbT[cb + 7][t] = b.w;
      const int zt = tid >> 4, zg = (tid & 15) << 3;
      const float4 z = make_float4(0.f, 0.f, 0.f, 0.f);
      *(float4*)&VT[zt][zg] = z;
      *(float4*)&VT[zt][zg + 4] = z;
    }
    __syncthreads();  // B0

    // ---- V = A Pb^T: per-wave partials, ds_add_f32 reduce into VT ----
    {
      float vp0[32], vp1[32];
#pragma unroll
      for (int t = 0; t < 32; ++t) { vp0[t] = 0.f; vp1[t] = 0.f; }
#pragma unroll
      for (int j = 0; j < 16; ++j) {
        const float a0 = A0[j], a1 = A1[j];
        const float* row = &PW.PbT[c0 + j][0];  // wave-uniform -> broadcast
#pragma unroll
        for (int t4 = 0; t4 < 8; ++t4) {
          const float4 pv = *(const float4*)&row[t4 * 4];
          vp0[4 * t4 + 0] = fmaf(a0, pv.x, vp0[4 * t4 + 0]);
          vp0[4 * t4 + 1] = fmaf(a0, pv.y, vp0[4 * t4 + 1]);
          vp0[4 * t4 + 2] = fmaf(a0, pv.z, vp0[4 * t4 + 2]);
          vp0[4 * t4 + 3] = fmaf(a0, pv.w, vp0[4 * t4 + 3]);
          vp1[4 * t4 + 0] = fmaf(a1, pv.x, vp1[4 * t4 + 0]);
          vp1[4 * t4 + 1] = fmaf(a1, pv.y, vp1[4 * t4 + 1]);
          vp1[4 * t4 + 2] = fmaf(a1, pv.z, vp1[4 * t4 + 2]);
          vp1[4 * t4 + 3] = fmaf(a1, pv.w, vp1[4 * t4 + 3]);
        }
      }
#pragma unroll
      for (int t = 0; t < 32; ++t) {
        unsafeAtomicAdd(&VT[t][lane], vp0[t]);       // ds_add_f32, no conflicts
        unsafeAtomicAdd(&VT[t][lane + 64], vp1[t]);
      }
    }
    __syncthreads();  // B1

    // ---- S = Pb V: one (d,t)+(d+16,t) pair per thread; Pb from L1 ----
    {
      const int t = tid & 31;
      const int d0 = tid >> 5;
      const float* prow0 = P + (i0 + d0) * NN;
      const float* prow1 = P + (i0 + d0 + 16) * NN;
      float s0 = 0.f, s1 = 0.f;
#pragma unroll
      for (int r4 = 0; r4 < 32; ++r4) {
        const float4 v4 = *(const float4*)&VT[t][r4 * 4];
        const float4 pa = *(const float4*)&prow0[r4 * 4];
        const float4 pb = *(const float4*)&prow1[r4 * 4];
        s0 = fmaf(pa.x, v4.x, s0); s0 = fmaf(pa.y, v4.y, s0);
        s0 = fmaf(pa.z, v4.z, s0); s0 = fmaf(pa.w, v4.w, s0);
        s1 = fmaf(pb.x, v4.x, s1); s1 = fmaf(pb.y, v4.y, s1);
        s1 = fmaf(pb.z, v4.z, s1); s1 = fmaf(pb.w, v4.w, s1);
      }
      Smat[d0][t] = s0;
      Smat[d0 + 16][t] = s1;
    }
    __syncthreads();  // B2

    // ---- scan: wave 0 only, register-resident (verified in round 2) ----
    if (wave == 0) {
      const int a = lane & 31;
      float Sreg[32], Ereg[32], Ureg[32];
#pragma unroll
      for (int j = 0; j < 32; ++j) {
        Sreg[j] = Smat[a][j];
        Ereg[j] = 0.f;
        Ureg[j] = 0.f;
      }
#pragma unroll
      for (int t = 0; t < BB; ++t) {
        const int i = i0 + t;
        const float x = Sreg[t];
        const float stt = __shfl(x, t, 64);
        const float s = 1.0f - stt;
        const int la = DD - NN + k;
        const bool active = (k < NN) && (i <= la);
        const float pr = active ? stt * ratio : 0.0f;
        const int kc = (k < NN) ? k : (NN - 1);
        const float uk =
            (kc < 64) ? __shfl(u_lo, kc, 64) : __shfl(u_hi, kc - 64, 64);
        const bool occupy = active && ((cumul + pr >= uk) || (i == la));
        float pivot = occupy ? (s - 1.0f) : s;
        pivot = (fabsf(pivot) < TINYF) ? TINYF : pivot;
        const float invp = 1.0f / pivot;
        if (lane == 0) {
          if (k < NN) out[k * DD + i] = pr;
          if (occupy) out[NN * DD + k] = (float)i;
          invpSh[t] = invp;
        }
        ratio = occupy ? 1.0f : (active ? ratio * s : ratio);
        cumul = occupy ? 0.0f : (cumul + pr);
        k += occupy ? 1 : 0;
        const float ec = x * invp;
        Ereg[t] = ec;
        float acc = 0.0f;
#pragma unroll
        for (int m = 0; m < t; ++m)
          acc = fmaf(Ureg[m], __shfl(Ereg[m], t, 64), acc);
        Ureg[t] = acc + ((a == t) ? 1.0f : 0.0f);
        const float y = x * invp;
#pragma unroll
        for (int b = t + 1; b < BB; ++b)
          Sreg[b] = fmaf(y, __shfl(x, b, 64), Sreg[b]);
      }
      if (lane < 32) {
#pragma unroll
        for (int j = 0; j < 8; ++j)
          *(float4*)&Umat[lane][4 * j] =
              make_float4(Ureg[4 * j], Ureg[4 * j + 1], Ureg[4 * j + 2],
                          Ureg[4 * j + 3]);
      }
      if (lane == 0) kSh = k;
    }
    __syncthreads();  // B3

    const bool last = (blk == DD / BB - 1) || (kSh >= NN);
    if (last) break;  // uniform; outputs complete

    // ---- W = V U  (Wmat raw row-major; WdT = W*invp transposed) ----
    {
      const int r = tid & 127;
      const int t0 = (tid >> 7) << 3;
      float wacc[8];
#pragma unroll
      for (int tt = 0; tt < 8; ++tt) wacc[tt] = 0.f;
      for (int j = 0; j < t0 + 8; ++j) {  // U[j][t]=0 for j>t
        const float vv = VT[j][r];
        const float4 ua = *(const float4*)&Umat[j][t0];
        const float4 ub = *(const float4*)&Umat[j][t0 + 4];
        wacc[0] = fmaf(vv, ua.x, wacc[0]);
        wacc[1] = fmaf(vv, ua.y, wacc[1]);
        wacc[2] = fmaf(vv, ua.z, wacc[2]);
        wacc[3] = fmaf(vv, ua.w, wacc[3]);
        wacc[4] = fmaf(vv, ub.x, wacc[4]);
        wacc[5] = fmaf(vv, ub.y, wacc[5]);
        wacc[6] = fmaf(vv, ub.z, wacc[6]);
        wacc[7] = fmaf(vv, ub.w, wacc[7]);
      }
      *(float4*)&PW.Wmat[r][t0] =
          make_float4(wacc[0], wacc[1], wacc[2], wacc[3]);
      *(float4*)&PW.Wmat[r][t0 + 4] =
          make_float4(wacc[4], wacc[5], wacc[6], wacc[7]);
      const float4 iva = *(const float4*)&invpSh[t0];
      const float4 ivb = *(const float4*)&invpSh[t0 + 4];
      WdT[t0 + 0][r] = wacc[0] * iva.x;
      WdT[t0 + 1][r] = wacc[1] * iva.y;
      WdT[t0 + 2][r] = wacc[2] * iva.z;
      WdT[t0 + 3][r] = wacc[3] * iva.w;
      WdT[t0 + 4][r] = wacc[4] * ivb.x;
      WdT[t0 + 5][r] = wacc[5] * ivb.y;
      WdT[t0 + 6][r] = wacc[6] * ivb.z;
      WdT[t0 + 7][r] = wacc[7] * ivb.w;
    }
    __syncthreads();  // B4

    // ---- A += Wd W^T (row-at-a-time to cap register pressure) ----
    {
      float wd[32];
#pragma unroll
      for (int t = 0; t < 32; ++t) wd[t] = WdT[t][lane];
#pragma unroll
      for (int j = 0; j < 16; ++j) {
        const float* wrow = &PW.Wmat[c0 + j][0];  // wave-uniform broadcast
        float acc = A0[j];
#pragma unroll
        for (int t8 = 0; t8 < 8; ++t8) {
          const float4 w4 = *(const float4*)&wrow[t8 * 4];
          acc = fmaf(wd[4 * t8 + 0], w4.x, acc);
          acc = fmaf(wd[4 * t8 + 1], w4.y, acc);
          acc = fmaf(wd[4 * t8 + 2], w4.z, acc);
          acc = fmaf(wd[4 * t8 + 3], w4.w, acc);
        }
        A0[j] = acc;
      }
#pragma unroll
      for (int t = 0; t < 32; ++t) wd[t] = WdT[t][lane + 64];
#pragma unroll
      for (int j = 0; j < 16; ++j) {
        const float* wrow = &PW.Wmat[c0 + j][0];
        float acc = A1[j];
#pragma unroll
        for (int t8 = 0; t8 < 8; ++t8) {
          const float4 w4 = *(const float4*)&wrow[t8 * 4];
          acc = fmaf(wd[4 * t8 + 0], w4.x, acc);
          acc = fmaf(wd[4 * t8 + 1], w4.y, acc);
          acc = fmaf(wd[4 * t8 + 2], w4.z, acc);
          acc = fmaf(wd[4 * t8 + 3], w4.w, acc);
        }
        A1[j] = acc;
      }
    }
    __syncthreads();  // B5: protect Wmat/WdT/VT before next block
  }
}

extern "C" void kernel_launch(void* const* d_in, const int* in_sizes, int n_in,
                              void* d_out, int out_size, void* d_ws,
                              size_t ws_size, hipStream_t stream) {
  const float* P = (const float*)d_in[0];  // (512, 128) row-major fp32
  const float* u = (const float*)d_in[1];  // (128,) fp32
  float* out = (float*)d_out;              // 65536 cond_probs + 128 positions
  hipLaunchKernelGGL(slater_blk3, dim3(1), dim3(NTH), 0, stream, P, u, out);
}

// Round 4
// 1743.426 us; speedup vs baseline: 1.2035x; 1.2035x over previous
//
#include <hip/hip_runtime.h>

// Slater-determinant ordered sampler, D=512 sites, N=128 particles.
//
// Blocked N x N inverse-block recursion (algebra verified, passed r2/r3):
//   per block of B=32 sites: S = Pb A Pb^T; register-resident single-wave
//   scan on S (decision logic identical to reference); A += (V U) D^-1 (V U)^T
//   with V = A Pb^T, U = (I - E_strict)^{-1} built during the scan.
//
// Round-4: kill the register spills that sank r2 (1258us) and r3 (2098us):
//   * __launch_bounds__(512, 2): 2 waves/EU -> 256-VGPR cap (r3's
//     amdgpu_waves_per_eu attr was ignored; VGPR_Count stayed 128).
//   * Every phase also fits ~110 live VGPRs so a 128 cap still works:
//     - V-phase in 2 half-passes (vp live 64 -> 32)
//     - scan: Ereg -> dead Smat storage (rows read once before the loop;
//       E[m][t] re-read at wave-uniform addresses = LDS broadcast)
//     - A-update: fused j-loop (also halves Wmat broadcast reads)
//   * u in LDS, not registers.
// 6 barriers/block (96 total); LDS 61.7 KB.

#define DD 512
#define NN 128
#define BB 32
#define NTH 512
#define TINYF 1e-30f

__global__ __launch_bounds__(NTH, 2)
void slater_blk4(const float* __restrict__ P, const float* __restrict__ u,
                 float* __restrict__ out) {
  const int tid  = threadIdx.x;
  const int wave = tid >> 6;
  const int lane = tid & 63;
  const int c0   = wave << 4;

  __shared__ union PWU {
    float PbT[128][36];   // PbT[c][t] = P[i0+t][c]; rows read wave-uniform
    float Wmat[128][36];  // W row-major (overlay; PbT dead after S-phase)
  } PW;
  __shared__ float VT[32][132];   // VT[t][r] = V[r][t]
  __shared__ float WdT[32][132];  // WdT[t][r] = W[r][t] * invp[t]
  __shared__ float Smat[32][33];  // S; rows reused as E rows during scan
  __shared__ float Umat[32][36];
  __shared__ float invpSh[32];
  __shared__ float ush[NN];
  __shared__ int   kSh;

  // Zero cond_probs (harness poisons d_out). positions all get written.
  {
    const float4 z = make_float4(0.f, 0.f, 0.f, 0.f);
    float4* o4 = (float4*)out;
#pragma unroll
    for (int j = 0; j < 32; ++j) o4[tid + j * NTH] = z;
  }
  if (tid < NN) ush[tid] = u[tid];

  // A = I_N: wave w owns cols [16w,16w+16); lane l owns rows {l, l+64}.
  float A0[16], A1[16];
#pragma unroll
  for (int j = 0; j < 16; ++j) {
    A0[j] = (lane == c0 + j) ? 1.0f : 0.0f;
    A1[j] = (lane + 64 == c0 + j) ? 1.0f : 0.0f;
  }

  // Scan state (only wave 0's copy is live across blocks).
  float ratio = 1.0f, cumul = 0.0f;
  int k = 0;

  for (int blk = 0; blk < DD / BB; ++blk) {
    const int i0 = blk * BB;

    // ---- stage PbT + zero VT ----
    {
      const int t = tid & 31, cb = (tid >> 5) << 3;
      const float* src = P + (i0 + t) * NN + cb;
      const float4 a = *(const float4*)src;
      const float4 b = *(const float4*)(src + 4);
      PW.PbT[cb + 0][t] = a.x; PW.PbT[cb + 1][t] = a.y;
      PW.PbT[cb + 2][t] = a.z; PW.PbT[cb + 3][t] = a.w;
      PW.PbT[cb + 4][t] = b.x; PW.PbT[cb + 5][t] = b.y;
      PW.PbT[cb + 6][t] = b.z; PW.PbT[cb + 7][t] = b.w;
      const int zt = tid >> 4, zg = (tid & 15) << 3;
      const float4 z = make_float4(0.f, 0.f, 0.f, 0.f);
      *(float4*)&VT[zt][zg] = z;
      *(float4*)&VT[zt][zg + 4] = z;
    }
    __syncthreads();  // B0

    // ---- V = A Pb^T: 2 half-passes, ds_add_f32 reduce into VT ----
#pragma unroll 1
    for (int half = 0; half < 2; ++half) {
      const int tb = half << 4;
      float vp0[16], vp1[16];
#pragma unroll
      for (int t = 0; t < 16; ++t) { vp0[t] = 0.f; vp1[t] = 0.f; }
#pragma unroll
      for (int j = 0; j < 16; ++j) {
        const float a0 = A0[j], a1 = A1[j];
        const float* row = &PW.PbT[c0 + j][tb];  // wave-uniform -> broadcast
#pragma unroll
        for (int t4 = 0; t4 < 4; ++t4) {
          const float4 pv = *(const float4*)&row[t4 * 4];
          vp0[4 * t4 + 0] = fmaf(a0, pv.x, vp0[4 * t4 + 0]);
          vp0[4 * t4 + 1] = fmaf(a0, pv.y, vp0[4 * t4 + 1]);
          vp0[4 * t4 + 2] = fmaf(a0, pv.z, vp0[4 * t4 + 2]);
          vp0[4 * t4 + 3] = fmaf(a0, pv.w, vp0[4 * t4 + 3]);
          vp1[4 * t4 + 0] = fmaf(a1, pv.x, vp1[4 * t4 + 0]);
          vp1[4 * t4 + 1] = fmaf(a1, pv.y, vp1[4 * t4 + 1]);
          vp1[4 * t4 + 2] = fmaf(a1, pv.z, vp1[4 * t4 + 2]);
          vp1[4 * t4 + 3] = fmaf(a1, pv.w, vp1[4 * t4 + 3]);
        }
      }
#pragma unroll
      for (int t = 0; t < 16; ++t) {
        unsafeAtomicAdd(&VT[tb + t][lane], vp0[t]);  // ds_add, conflict-free
        unsafeAtomicAdd(&VT[tb + t][lane + 64], vp1[t]);
      }
    }
    __syncthreads();  // B1

    // ---- S = Pb V: one (d,t)+(d+16,t) pair per thread; Pb from L1 ----
    {
      const int t = tid & 31;
      const int d0 = tid >> 5;
      const float* prow0 = P + (i0 + d0) * NN;
      const float* prow1 = P + (i0 + d0 + 16) * NN;
      float s0 = 0.f, s1 = 0.f;
#pragma unroll
      for (int r4 = 0; r4 < 32; ++r4) {
        const float4 v4 = *(const float4*)&VT[t][r4 * 4];
        const float4 pa = *(const float4*)&prow0[r4 * 4];
        const float4 pb = *(const float4*)&prow1[r4 * 4];
        s0 = fmaf(pa.x, v4.x, s0); s0 = fmaf(pa.y, v4.y, s0);
        s0 = fmaf(pa.z, v4.z, s0); s0 = fmaf(pa.w, v4.w, s0);
        s1 = fmaf(pb.x, v4.x, s1); s1 = fmaf(pb.y, v4.y, s1);
        s1 = fmaf(pb.z, v4.z, s1); s1 = fmaf(pb.w, v4.w, s1);
      }
      Smat[d0][t] = s0;
      Smat[d0 + 16][t] = s1;
    }
    __syncthreads();  // B2

    // ---- scan: wave 0 only, register-resident ----
    if (wave == 0) {
      const int a = lane & 31;
      float Sreg[32], Ureg[32];
#pragma unroll
      for (int j = 0; j < 32; ++j) {
        Sreg[j] = Smat[a][j];  // Smat rows dead after this (reused for E)
        Ureg[j] = 0.f;
      }
#pragma unroll 1
      for (int t = 0; t < BB; ++t) {
        const int i = i0 + t;
        const float x = Sreg[t];
        const float stt = __shfl(x, t, 64);
        const float s = 1.0f - stt;
        const int la = DD - NN + k;
        const bool active = (k < NN) && (i <= la);
        const float pr = active ? stt * ratio : 0.0f;
        const float uk = ush[(k < NN) ? k : (NN - 1)];
        const bool occupy = active && ((cumul + pr >= uk) || (i == la));
        float pivot = occupy ? (s - 1.0f) : s;
        pivot = (fabsf(pivot) < TINYF) ? TINYF : pivot;
        const float invp = 1.0f / pivot;
        if (lane == 0) {
          if (k < NN) out[k * DD + i] = pr;
          if (occupy) out[NN * DD + k] = (float)i;
          invpSh[t] = invp;
        }
        ratio = occupy ? 1.0f : (active ? ratio * s : ratio);
        cumul = occupy ? 0.0f : (cumul + pr);
        k += occupy ? 1 : 0;
        // E row t into dead Smat storage: E[t][a] = S~[t][a] * invp
        Smat[t][a] = x * invp;
        // U column t: u_t[a] = sum_{m<t} U[a][m] * E[m][t]  (broadcast reads)
        float acc = 0.0f;
        for (int m = 0; m < t; ++m)
          acc = fmaf(Ureg[m], Smat[m][t], acc);
        Ureg[t] = acc + ((a == t) ? 1.0f : 0.0f);
        // trailing rank-1 update of S~ (symmetric)
        const float y = x * invp;
#pragma unroll
        for (int b = t + 1; b < BB; ++b)
          Sreg[b] = fmaf(y, __shfl(x, b, 64), Sreg[b]);
      }
      if (lane < 32) {
#pragma unroll
        for (int j = 0; j < 8; ++j)
          *(float4*)&Umat[lane][4 * j] =
              make_float4(Ureg[4 * j], Ureg[4 * j + 1], Ureg[4 * j + 2],
                          Ureg[4 * j + 3]);
      }
      if (lane == 0) kSh = k;
    }
    __syncthreads();  // B3

    const bool last = (blk == DD / BB - 1) || (kSh >= NN);
    if (last) break;  // uniform; remaining outputs are correctly zero

    // ---- W = V U  (Wmat raw row-major; WdT = W*invp transposed) ----
    {
      const int r = tid & 127;
      const int t0 = (tid >> 7) << 3;
      float wacc[8];
#pragma unroll
      for (int tt = 0; tt < 8; ++tt) wacc[tt] = 0.f;
      for (int j = 0; j < t0 + 8; ++j) {  // U[j][t]=0 for j>t
        const float vv = VT[j][r];
        const float4 ua = *(const float4*)&Umat[j][t0];
        const float4 ub = *(const float4*)&Umat[j][t0 + 4];
        wacc[0] = fmaf(vv, ua.x, wacc[0]);
        wacc[1] = fmaf(vv, ua.y, wacc[1]);
        wacc[2] = fmaf(vv, ua.z, wacc[2]);
        wacc[3] = fmaf(vv, ua.w, wacc[3]);
        wacc[4] = fmaf(vv, ub.x, wacc[4]);
        wacc[5] = fmaf(vv, ub.y, wacc[5]);
        wacc[6] = fmaf(vv, ub.z, wacc[6]);
        wacc[7] = fmaf(vv, ub.w, wacc[7]);
      }
      *(float4*)&PW.Wmat[r][t0] =
          make_float4(wacc[0], wacc[1], wacc[2], wacc[3]);
      *(float4*)&PW.Wmat[r][t0 + 4] =
          make_float4(wacc[4], wacc[5], wacc[6], wacc[7]);
      const float4 iva = *(const float4*)&invpSh[t0];
      const float4 ivb = *(const float4*)&invpSh[t0 + 4];
      WdT[t0 + 0][r] = wacc[0] * iva.x;
      WdT[t0 + 1][r] = wacc[1] * iva.y;
      WdT[t0 + 2][r] = wacc[2] * iva.z;
      WdT[t0 + 3][r] = wacc[3] * iva.w;
      WdT[t0 + 4][r] = wacc[4] * ivb.x;
      WdT[t0 + 5][r] = wacc[5] * ivb.y;
      WdT[t0 + 6][r] = wacc[6] * ivb.z;
      WdT[t0 + 7][r] = wacc[7] * ivb.w;
    }
    __syncthreads();  // B4

    // ---- A += Wd W^T (fused: both row-halves share each Wmat row read) ----
    {
      float wd0[32], wd1[32];
#pragma unroll
      for (int t = 0; t < 32; ++t) {
        wd0[t] = WdT[t][lane];
        wd1[t] = WdT[t][lane + 64];
      }
#pragma unroll
      for (int j = 0; j < 16; ++j) {
        const float* wrow = &PW.Wmat[c0 + j][0];  // wave-uniform broadcast
        float a0 = A0[j], a1 = A1[j];
#pragma unroll
        for (int t4 = 0; t4 < 8; ++t4) {
          const float4 w4 = *(const float4*)&wrow[t4 * 4];
          a0 = fmaf(wd0[4 * t4 + 0], w4.x, a0);
          a0 = fmaf(wd0[4 * t4 + 1], w4.y, a0);
          a0 = fmaf(wd0[4 * t4 + 2], w4.z, a0);
          a0 = fmaf(wd0[4 * t4 + 3], w4.w, a0);
          a1 = fmaf(wd1[4 * t4 + 0], w4.x, a1);
          a1 = fmaf(wd1[4 * t4 + 1], w4.y, a1);
          a1 = fmaf(wd1[4 * t4 + 2], w4.z, a1);
          a1 = fmaf(wd1[4 * t4 + 3], w4.w, a1);
        }
        A0[j] = a0;
        A1[j] = a1;
      }
    }
    __syncthreads();  // B5: protect Wmat/WdT/VT before next block
  }
}

extern "C" void kernel_launch(void* const* d_in, const int* in_sizes, int n_in,
                              void* d_out, int out_size, void* d_ws,
                              size_t ws_size, hipStream_t stream) {
  const float* P = (const float*)d_in[0];  // (512, 128) row-major fp32
  const float* u = (const float*)d_in[1];  // (128,) fp32
  float* out = (float*)d_out;              // 65536 cond_probs + 128 positions
  hipLaunchKernelGGL(slater_blk4, dim3(1), dim3(NTH), 0, stream, P, u, out);
}

// Round 5
// 1137.050 us; speedup vs baseline: 1.8453x; 1.5333x over previous
//
#include <hip/hip_runtime.h>

// Slater-determinant ordered sampler, D=512 sites, N=128 particles.
//
// Blocked N x N inverse-block recursion (algebra verified, passed r2-r4):
//   per block of B=32 sites: S = Pb A Pb^T; single-wave register scan on S
//   (decision logic identical to reference); A += (V U) D^-1 (V U)^T with
//   V = A Pb^T, U = unit-upper from the scan.
//
// Round-5: kill the scan's latency stalls (r4: runtime-bounded LDS loop in
// U-build = ~1M stall cycles; CU was 90% idle):
//  * U-build fused into the rank-1 broadcast loop (same values, same order),
//    FULLY unrolled -> v_readlane (SGPR broadcast, ~4cyc) instead of LDS.
//  * P staging for block b+1 done by waves 1-4 while wave 0 scans
//    (double-buffered PbT; Wmat overlays the dead current PbT).
//  * A-update builds Wd = W*invp on the fly (no WdT buffer -> LDS 63.2 KB).
// 6 barriers/block. All phases fit the 256-VGPR cap (launch_bounds(512,2)).

#define DD 512
#define NN 128
#define BB 32
#define NTH 512
#define TINYF 1e-30f

__device__ __forceinline__ float rdlane(float v, int l) {
  return __uint_as_float(__builtin_amdgcn_readlane(__float_as_uint(v), l));
}

__global__ __launch_bounds__(NTH, 2)
void slater_blk5(const float* __restrict__ P, const float* __restrict__ u,
                 float* __restrict__ out) {
  const int tid  = threadIdx.x;
  const int wave = tid >> 6;
  const int lane = tid & 63;
  const int c0   = wave << 4;

  __shared__ __align__(16) float buf[2][128][36];  // PbT (dbl-buf) / Wmat
  __shared__ __align__(16) float VT[32][132];      // VT[t][r] = V[r][t]
  __shared__ __align__(16) float Smat[32][33];
  __shared__ __align__(16) float Umat[32][36];
  __shared__ __align__(16) float invpSh[32];
  __shared__ float ush[NN];
  __shared__ int kSh;

  // Zero cond_probs (harness poisons d_out); positions all get written.
  {
    const float4 z = make_float4(0.f, 0.f, 0.f, 0.f);
    float4* o4 = (float4*)out;
#pragma unroll
    for (int j = 0; j < 32; ++j) o4[tid + j * NTH] = z;
  }
  if (tid < NN) ush[tid] = u[tid];

  // Stage block 0 into buf[0]: PbT[c][t] = P[t][c].
  {
    const int t = tid & 31, cb = (tid >> 5) << 3;
    const float* src = P + t * NN + cb;
    const float4 a = *(const float4*)src;
    const float4 b = *(const float4*)(src + 4);
    buf[0][cb + 0][t] = a.x; buf[0][cb + 1][t] = a.y;
    buf[0][cb + 2][t] = a.z; buf[0][cb + 3][t] = a.w;
    buf[0][cb + 4][t] = b.x; buf[0][cb + 5][t] = b.y;
    buf[0][cb + 6][t] = b.z; buf[0][cb + 7][t] = b.w;
  }
  // Zero VT (accumulated by ds_add atomics).
  {
    const float4 z = make_float4(0.f, 0.f, 0.f, 0.f);
    float4* v4 = (float4*)VT;
    for (int j = tid; j < (32 * 132) / 4; j += NTH) v4[j] = z;
  }

  // A = I_N: wave w owns cols [16w,16w+16); lane l owns rows {l, l+64}.
  float A0[16], A1[16];
#pragma unroll
  for (int j = 0; j < 16; ++j) {
    A0[j] = (lane == c0 + j) ? 1.0f : 0.0f;
    A1[j] = (lane + 64 == c0 + j) ? 1.0f : 0.0f;
  }

  // Scan state (only wave 0's copy is live across blocks).
  float ratio = 1.0f, cumul = 0.0f, uk_cur = u[0];
  int k = 0;

  __syncthreads();  // B0 (init)

  for (int blk = 0; blk < DD / BB; ++blk) {
    const int i0 = blk * BB;
    float (*pb)[36] = buf[blk & 1];

    // ---- V = A Pb^T: 2 half-passes, ds_add_f32 reduce into VT ----
#pragma unroll 1
    for (int half = 0; half < 2; ++half) {
      const int tb = half << 4;
      float vp0[16], vp1[16];
#pragma unroll
      for (int t = 0; t < 16; ++t) { vp0[t] = 0.f; vp1[t] = 0.f; }
#pragma unroll
      for (int j = 0; j < 16; ++j) {
        const float a0 = A0[j], a1 = A1[j];
        const float* row = &pb[c0 + j][tb];  // wave-uniform -> broadcast
#pragma unroll
        for (int t4 = 0; t4 < 4; ++t4) {
          const float4 pv = *(const float4*)&row[t4 * 4];
          vp0[4 * t4 + 0] = fmaf(a0, pv.x, vp0[4 * t4 + 0]);
          vp0[4 * t4 + 1] = fmaf(a0, pv.y, vp0[4 * t4 + 1]);
          vp0[4 * t4 + 2] = fmaf(a0, pv.z, vp0[4 * t4 + 2]);
          vp0[4 * t4 + 3] = fmaf(a0, pv.w, vp0[4 * t4 + 3]);
          vp1[4 * t4 + 0] = fmaf(a1, pv.x, vp1[4 * t4 + 0]);
          vp1[4 * t4 + 1] = fmaf(a1, pv.y, vp1[4 * t4 + 1]);
          vp1[4 * t4 + 2] = fmaf(a1, pv.z, vp1[4 * t4 + 2]);
          vp1[4 * t4 + 3] = fmaf(a1, pv.w, vp1[4 * t4 + 3]);
        }
      }
#pragma unroll
      for (int t = 0; t < 16; ++t) {
        unsafeAtomicAdd(&VT[tb + t][lane], vp0[t]);  // ds_add, conflict-free
        unsafeAtomicAdd(&VT[tb + t][lane + 64], vp1[t]);
      }
    }
    __syncthreads();  // B1

    // ---- S = Pb V: one (d,t)+(d+16,t) pair per thread; Pb from L1 ----
    {
      const int t = tid & 31;
      const int d0 = tid >> 5;
      const float* prow0 = P + (i0 + d0) * NN;
      const float* prow1 = P + (i0 + d0 + 16) * NN;
      float s0 = 0.f, s1 = 0.f;
#pragma unroll
      for (int r4 = 0; r4 < 32; ++r4) {
        const float4 v4 = *(const float4*)&VT[t][r4 * 4];
        const float4 pa = *(const float4*)&prow0[r4 * 4];
        const float4 pc = *(const float4*)&prow1[r4 * 4];
        s0 = fmaf(pa.x, v4.x, s0); s0 = fmaf(pa.y, v4.y, s0);
        s0 = fmaf(pa.z, v4.z, s0); s0 = fmaf(pa.w, v4.w, s0);
        s1 = fmaf(pc.x, v4.x, s1); s1 = fmaf(pc.y, v4.y, s1);
        s1 = fmaf(pc.z, v4.z, s1); s1 = fmaf(pc.w, v4.w, s1);
      }
      Smat[d0][t] = s0;
      Smat[d0 + 16][t] = s1;
    }
    __syncthreads();  // B2

    // ---- wave 0: scan.  waves 1-4: stage next block's PbT ----
    if (wave == 0) {
      const int a = lane & 31;
      float Sreg[32], Ucols[32];
#pragma unroll
      for (int j = 0; j < 32; ++j) {
        Sreg[j] = Smat[a][j];
        Ucols[j] = 0.f;
      }
#pragma unroll 32
      for (int t = 0; t < BB; ++t) {
        const int i = i0 + t;
        const float x = Sreg[t];
        const float stt = rdlane(x, t);
        const float s = 1.0f - stt;
        const int la = DD - NN + k;
        const bool active = (k < NN) && (i <= la);
        const float pr = active ? stt * ratio : 0.0f;
        const bool occupy = active && ((cumul + pr >= uk_cur) || (i == la));
        float pivot = occupy ? (s - 1.0f) : s;
        pivot = (fabsf(pivot) < TINYF) ? TINYF : pivot;
        const float invp = 1.0f / pivot;
        if (lane == 0) {
          if (k < NN) out[k * DD + i] = pr;
          if (occupy) out[NN * DD + k] = (float)i;
          invpSh[t] = invp;
        }
        ratio = occupy ? 1.0f : (active ? ratio * s : ratio);
        cumul = occupy ? 0.0f : (cumul + pr);
        k += occupy ? 1 : 0;
        uk_cur = ush[(k < NN) ? k : (NN - 1)];  // prefetch for next step
        Ucols[t] += (a == t) ? 1.0f : 0.0f;     // identity before use
        const float y = x * invp;
        const float g = Ucols[t] * invp;
#pragma unroll
        for (int b = t + 1; b < BB; ++b) {
          const float xb = rdlane(x, b);        // SGPR broadcast, ~4 cyc
          Sreg[b] = fmaf(y, xb, Sreg[b]);       // S~ rank-1 (r2-r4 values)
          Ucols[b] = fmaf(g, xb, Ucols[b]);     // fused U-build (same E vals)
        }
      }
      if (lane < 32) {
#pragma unroll
        for (int j8 = 0; j8 < 8; ++j8)
          *(float4*)&Umat[lane][4 * j8] =
              make_float4(Ucols[4 * j8], Ucols[4 * j8 + 1],
                          Ucols[4 * j8 + 2], Ucols[4 * j8 + 3]);
      }
      if (lane == 0) kSh = k;
    } else if (wave <= 4 && blk + 1 < DD / BB) {
      // Stage PbT for block blk+1 into the other buffer (off critical path).
      const int q = tid - 64;                  // 0..255
      const int t = q & 31, cb = (q >> 5) << 4;  // 8 groups x 16 cols
      const float* src = P + (i0 + BB + t) * NN + cb;
      const float4 a = *(const float4*)src;
      const float4 b = *(const float4*)(src + 4);
      const float4 c = *(const float4*)(src + 8);
      const float4 d = *(const float4*)(src + 12);
      float (*nb)[36] = buf[(blk & 1) ^ 1];
      nb[cb + 0][t] = a.x;  nb[cb + 1][t] = a.y;
      nb[cb + 2][t] = a.z;  nb[cb + 3][t] = a.w;
      nb[cb + 4][t] = b.x;  nb[cb + 5][t] = b.y;
      nb[cb + 6][t] = b.z;  nb[cb + 7][t] = b.w;
      nb[cb + 8][t] = c.x;  nb[cb + 9][t] = c.y;
      nb[cb + 10][t] = c.z; nb[cb + 11][t] = c.w;
      nb[cb + 12][t] = d.x; nb[cb + 13][t] = d.y;
      nb[cb + 14][t] = d.z; nb[cb + 15][t] = d.w;
    }
    __syncthreads();  // B3

    if (blk == DD / BB - 1 || kSh >= NN) break;  // uniform; outputs complete

    // ---- W = V U (raw, into pb over dead PbT); full 32-j unroll
    //      (U[j][t] = 0 for j > t -> extra terms are exact zeros) ----
    {
      const int r = tid & 127;
      const int t0 = (tid >> 7) << 3;
      float wacc[8];
#pragma unroll
      for (int tt = 0; tt < 8; ++tt) wacc[tt] = 0.f;
#pragma unroll
      for (int j = 0; j < 32; ++j) {
        const float vv = VT[j][r];
        const float4 ua = *(const float4*)&Umat[j][t0];
        const float4 ub = *(const float4*)&Umat[j][t0 + 4];
        wacc[0] = fmaf(vv, ua.x, wacc[0]);
        wacc[1] = fmaf(vv, ua.y, wacc[1]);
        wacc[2] = fmaf(vv, ua.z, wacc[2]);
        wacc[3] = fmaf(vv, ua.w, wacc[3]);
        wacc[4] = fmaf(vv, ub.x, wacc[4]);
        wacc[5] = fmaf(vv, ub.y, wacc[5]);
        wacc[6] = fmaf(vv, ub.z, wacc[6]);
        wacc[7] = fmaf(vv, ub.w, wacc[7]);
      }
      *(float4*)&pb[r][t0] = make_float4(wacc[0], wacc[1], wacc[2], wacc[3]);
      *(float4*)&pb[r][t0 + 4] =
          make_float4(wacc[4], wacc[5], wacc[6], wacc[7]);
    }
    __syncthreads();  // B4

    // ---- A += (W invp) W^T ----
    {
      float iv[32];
#pragma unroll
      for (int j8 = 0; j8 < 8; ++j8) {
        const float4 q = *(const float4*)&invpSh[4 * j8];
        iv[4 * j8] = q.x; iv[4 * j8 + 1] = q.y;
        iv[4 * j8 + 2] = q.z; iv[4 * j8 + 3] = q.w;
      }
      float wd0[32], wd1[32];
#pragma unroll
      for (int t8 = 0; t8 < 8; ++t8) {
        const float4 wa = *(const float4*)&pb[lane][4 * t8];
        const float4 wb = *(const float4*)&pb[lane + 64][4 * t8];
        wd0[4 * t8 + 0] = wa.x * iv[4 * t8 + 0];
        wd0[4 * t8 + 1] = wa.y * iv[4 * t8 + 1];
        wd0[4 * t8 + 2] = wa.z * iv[4 * t8 + 2];
        wd0[4 * t8 + 3] = wa.w * iv[4 * t8 + 3];
        wd1[4 * t8 + 0] = wb.x * iv[4 * t8 + 0];
        wd1[4 * t8 + 1] = wb.y * iv[4 * t8 + 1];
        wd1[4 * t8 + 2] = wb.z * iv[4 * t8 + 2];
        wd1[4 * t8 + 3] = wb.w * iv[4 * t8 + 3];
      }
#pragma unroll
      for (int j = 0; j < 16; ++j) {
        const float* wrow = &pb[c0 + j][0];  // wave-uniform broadcast
        float a0 = A0[j], a1 = A1[j];
#pragma unroll
        for (int t4 = 0; t4 < 8; ++t4) {
          const float4 w4 = *(const float4*)&wrow[t4 * 4];
          a0 = fmaf(wd0[4 * t4 + 0], w4.x, a0);
          a0 = fmaf(wd0[4 * t4 + 1], w4.y, a0);
          a0 = fmaf(wd0[4 * t4 + 2], w4.z, a0);
          a0 = fmaf(wd0[4 * t4 + 3], w4.w, a0);
          a1 = fmaf(wd1[4 * t4 + 0], w4.x, a1);
          a1 = fmaf(wd1[4 * t4 + 1], w4.y, a1);
          a1 = fmaf(wd1[4 * t4 + 2], w4.z, a1);
          a1 = fmaf(wd1[4 * t4 + 3], w4.w, a1);
        }
        A0[j] = a0;
        A1[j] = a1;
      }
    }
    __syncthreads();  // B5

    // ---- zero VT for the next block's atomics ----
    {
      const float4 z = make_float4(0.f, 0.f, 0.f, 0.f);
      float4* v4 = (float4*)VT;
      for (int j = tid; j < (32 * 132) / 4; j += NTH) v4[j] = z;
    }
    __syncthreads();  // B6
  }
}

extern "C" void kernel_launch(void* const* d_in, const int* in_sizes, int n_in,
                              void* d_out, int out_size, void* d_ws,
                              size_t ws_size, hipStream_t stream) {
  const float* P = (const float*)d_in[0];  // (512, 128) row-major fp32
  const float* u = (const float*)d_in[1];  // (128,) fp32
  float* out = (float*)d_out;              // 65536 cond_probs + 128 positions
  hipLaunchKernelGGL(slater_blk5, dim3(1), dim3(NTH), 0, stream, P, u, out);
}